// Round 3
// baseline (438.374 us; speedup 1.0000x reference)
//
#include <hip/hip_runtime.h>
#include <stdint.h>

// Problem constants
#define S_DIM 512
#define B_DIM 64
#define T_DIM 768
#define A_DIM 512
#define H1_DIM 768
#define H2_DIM 640
#define N_DIM (H1_DIM + H2_DIM)   // 1408 combined hidden cols
#define M_DIM (S_DIM * B_DIM)     // 32768 rows
#define K_DIM T_DIM               // 768

typedef short s16x8 __attribute__((ext_vector_type(8)));
typedef float f32x16 __attribute__((ext_vector_type(16)));

__device__ __forceinline__ unsigned short f2bf(float f) {
    unsigned u = __float_as_uint(f);
    u += 0x7fffu + ((u >> 16) & 1u);   // round-to-nearest-even
    return (unsigned short)(u >> 16);
}

// --- convert text_seq fp32 -> bf16 (flat (M,K)) ---
__global__ __launch_bounds__(256) void convA_kernel(const float* __restrict__ ts,
                                                    unsigned short* __restrict__ Abf) {
    int i = blockIdx.x * 256 + threadIdx.x;   // over M*K/4 float4 groups
    float4 v = ((const float4*)ts)[i];
    ushort4 o;
    o.x = f2bf(v.x); o.y = f2bf(v.y); o.z = f2bf(v.z); o.w = f2bf(v.w);
    ((ushort4*)Abf)[i] = o;
}

// --- build combined B^T bf16: Bt[n][k], n<768 from W11[:T], else W12[:T] ---
__global__ __launch_bounds__(256) void convW_kernel(const float* __restrict__ W11,
                                                    const float* __restrict__ W12,
                                                    unsigned short* __restrict__ Bt) {
    int e = blockIdx.x * 256 + threadIdx.x;   // N_DIM*K_DIM
    int n = e / K_DIM, k = e % K_DIM;
    float v = (n < H1_DIM) ? W11[k * H1_DIM + n] : W12[k * H2_DIM + (n - H1_DIM)];
    Bt[e] = f2bf(v);
}

// --- per-batch bias c[b][n] = text@W11[T:] + b11 | anp@W12[T:] + b12 (fp32) ---
__global__ __launch_bounds__(256) void bias_kernel(const float* __restrict__ text,
                                                   const float* __restrict__ anp,
                                                   const float* __restrict__ W11,
                                                   const float* __restrict__ b11,
                                                   const float* __restrict__ W12,
                                                   const float* __restrict__ b12,
                                                   float* __restrict__ cbias) {
    int e = blockIdx.x * 256 + threadIdx.x;   // B_DIM*N_DIM
    int b = e / N_DIM, n = e % N_DIM;
    float a0 = 0.f, a1 = 0.f, a2 = 0.f, a3 = 0.f, base;
    if (n < H1_DIM) {
        base = b11[n];
        const float* w = W11 + (size_t)T_DIM * H1_DIM + n;
        const float* x = text + b * T_DIM;
        for (int k = 0; k < T_DIM; k += 4) {
            a0 = fmaf(x[k],     w[(size_t)k * H1_DIM],       a0);
            a1 = fmaf(x[k + 1], w[(size_t)(k + 1) * H1_DIM], a1);
            a2 = fmaf(x[k + 2], w[(size_t)(k + 2) * H1_DIM], a2);
            a3 = fmaf(x[k + 3], w[(size_t)(k + 3) * H1_DIM], a3);
        }
    } else {
        int n2 = n - H1_DIM;
        base = b12[n2];
        const float* w = W12 + (size_t)T_DIM * H2_DIM + n2;
        const float* x = anp + b * A_DIM;
        for (int k = 0; k < A_DIM; k += 4) {
            a0 = fmaf(x[k],     w[(size_t)k * H2_DIM],       a0);
            a1 = fmaf(x[k + 1], w[(size_t)(k + 1) * H2_DIM], a1);
            a2 = fmaf(x[k + 2], w[(size_t)(k + 2) * H2_DIM], a2);
            a3 = fmaf(x[k + 3], w[(size_t)(k + 3) * H2_DIM], a3);
        }
    }
    cbias[e] = base + ((a0 + a1) + (a2 + a3));
}

// --- main: bf16 MFMA GEMM (32x32x16) with fused tanh-dot epilogue -> scores [2][B][S] ---
#define BM 256
#define BN 128
#define BK 64

__global__ __launch_bounds__(256, 2) void gemm_score_kernel(
        const unsigned short* __restrict__ A,    // (M,K) bf16
        const unsigned short* __restrict__ Bt,   // (N,K) bf16
        const float* __restrict__ cbias,         // (B,N)
        const float* __restrict__ W21,           // (768)
        const float* __restrict__ W22,           // (640)
        float* __restrict__ score) {             // [2][B][S] pre-zeroed
    __shared__ __align__(16) unsigned short As[BM * BK];   // 32 KB
    __shared__ __align__(16) unsigned short Bs[BN * BK];   // 16 KB
    const int tid  = threadIdx.x;
    const int m0   = blockIdx.x * BM;
    const int n0   = blockIdx.y * BN;
    const int lane = tid & 63;
    const int wave = tid >> 6;
    const int wm   = wave & 1;       // 2x2 waves: wave tile 128x64
    const int wn   = wave >> 1;
    const int l31  = lane & 31;
    const int h5   = lane >> 5;

    f32x16 acc[4][2] = {};           // 4x2 subtiles of 32x32 per wave

    // global_load_lds staging: each instr covers 8 rows x 64 k (1 KB contiguous LDS)
    const int wrow = lane >> 3;          // 0..7 row within 8-row group
    const int kof  = (lane & 7) * 8;     // bf16 element offset within row

    for (int k0 = 0; k0 < K_DIM; k0 += BK) {
        #pragma unroll
        for (int p = 0; p < 8; ++p) {    // A: 256 rows, wave stages 64
            const int r0 = wave * 64 + p * 8;
            __builtin_amdgcn_global_load_lds(
                (__attribute__((address_space(1))) void*)&A[(size_t)(m0 + r0 + wrow) * K_DIM + k0 + kof],
                (__attribute__((address_space(3))) void*)&As[r0 * BK],
                16, 0, 0);
        }
        #pragma unroll
        for (int p = 0; p < 4; ++p) {    // B: 128 rows, wave stages 32
            const int r0 = wave * 32 + p * 8;
            __builtin_amdgcn_global_load_lds(
                (__attribute__((address_space(1))) void*)&Bt[(size_t)(n0 + r0 + wrow) * K_DIM + k0 + kof],
                (__attribute__((address_space(3))) void*)&Bs[r0 * BK],
                16, 0, 0);
        }
        __syncthreads();
        #pragma unroll
        for (int kk = 0; kk < BK; kk += 16) {
            s16x8 af[4], bf[2];
            #pragma unroll
            for (int i = 0; i < 4; ++i)
                af[i] = *(const s16x8*)&As[(wm * 128 + i * 32 + l31) * BK + kk + h5 * 8];
            #pragma unroll
            for (int j = 0; j < 2; ++j)
                bf[j] = *(const s16x8*)&Bs[(wn * 64 + j * 32 + l31) * BK + kk + h5 * 8];
            #pragma unroll
            for (int i = 0; i < 4; ++i)
                #pragma unroll
                for (int j = 0; j < 2; ++j)
                    acc[i][j] = __builtin_amdgcn_mfma_f32_32x32x16_bf16(af[i], bf[j], acc[i][j], 0, 0, 0);
        }
        __syncthreads();
    }

    // Epilogue: score[half][b][s] += sum_n tanh(acc + c[b][n]) * w2[n]
    // 32x32 C/D layout: col = lane&31, row = (reg&3) + 8*(reg>>2) + 4*(lane>>5)
    const int half = (n0 >= H1_DIM) ? 1 : 0;     // 768 = 6*128, tiles never straddle
    const float* w2p = half ? (W22 - H1_DIM) : W21;
    int   ncol[2];
    float w2v[2];
    #pragma unroll
    for (int j = 0; j < 2; ++j) {
        ncol[j] = n0 + wn * 64 + j * 32 + l31;
        w2v[j]  = w2p[ncol[j]];
    }
    float* sc = score + half * M_DIM;
    #pragma unroll
    for (int i = 0; i < 4; ++i) {
        #pragma unroll
        for (int r = 0; r < 16; ++r) {
            int row_local = wm * 128 + i * 32 + (r & 3) + 8 * (r >> 2) + 4 * h5;
            int b = row_local & (B_DIM - 1);                   // m0 % 64 == 0
            int s = (m0 + row_local) >> 6;
            float v = 0.f;
            #pragma unroll
            for (int j = 0; j < 2; ++j) {
                float pre = acc[i][j][r] + cbias[b * N_DIM + ncol[j]];
                float ex  = __expf(2.f * pre);                 // tanh(x)=1-2/(e^{2x}+1)
                float th  = 1.f - 2.f * __builtin_amdgcn_rcpf(ex + 1.f);
                v = fmaf(th, w2v[j], v);
            }
            v += __shfl_xor(v, 1);    // reduce over 32 cols (xor stays in 32-half)
            v += __shfl_xor(v, 2);
            v += __shfl_xor(v, 4);
            v += __shfl_xor(v, 8);
            v += __shfl_xor(v, 16);
            if (l31 == 0) atomicAdd(&sc[b * S_DIM + s], v);
        }
    }
}

// --- softmax over S per (b, half); wsum[b][s] = w1 + w2; one block per b ---
__global__ __launch_bounds__(512) void softmax_kernel(const float* __restrict__ score,
                                                      float* __restrict__ wsum) {
    const int b = blockIdx.x, s = threadIdx.x;   // 512 threads = 512 s
    __shared__ float redm[16], reds[16];
    float v0 = score[b * S_DIM + s];
    float v1 = score[M_DIM + b * S_DIM + s];
    float m0 = v0, m1 = v1;
    #pragma unroll
    for (int off = 32; off > 0; off >>= 1) {
        m0 = fmaxf(m0, __shfl_xor(m0, off));
        m1 = fmaxf(m1, __shfl_xor(m1, off));
    }
    const int w = s >> 6;
    if ((s & 63) == 0) { redm[w] = m0; redm[8 + w] = m1; }
    __syncthreads();
    m0 = redm[0]; m1 = redm[8];
    #pragma unroll
    for (int i = 1; i < 8; ++i) { m0 = fmaxf(m0, redm[i]); m1 = fmaxf(m1, redm[8 + i]); }
    float e0 = expf(v0 - m0), e1 = expf(v1 - m1);
    float s0 = e0, s1 = e1;
    #pragma unroll
    for (int off = 32; off > 0; off >>= 1) {
        s0 += __shfl_xor(s0, off);
        s1 += __shfl_xor(s1, off);
    }
    if ((s & 63) == 0) { reds[w] = s0; reds[8 + w] = s1; }
    __syncthreads();
    s0 = reds[0]; s1 = reds[8];
    #pragma unroll
    for (int i = 1; i < 8; ++i) { s0 += reds[i]; s1 += reds[8 + i]; }
    wsum[b * S_DIM + s] = e0 / s0 + e1 / s1;
}

// --- out[b,t] = (0.5/S) * sum_s wsum[b][s] * ts[s,b,t], s-split over grid.y ---
__global__ __launch_bounds__(256) void wmean_kernel(const float* __restrict__ ts,
                                                    const float* __restrict__ wsum,
                                                    float* __restrict__ out) {
    int e = blockIdx.x * 256 + threadIdx.x;   // over B*T
    int s0 = blockIdx.y * 32;
    int b = e / T_DIM, t = e % T_DIM;
    float a0 = 0.f, a1 = 0.f;
    #pragma unroll 4
    for (int s = s0; s < s0 + 32; s += 2) {
        a0 = fmaf(wsum[b * S_DIM + s],     ts[(size_t)(s * B_DIM + b) * T_DIM + t],       a0);
        a1 = fmaf(wsum[b * S_DIM + s + 1], ts[(size_t)((s + 1) * B_DIM + b) * T_DIM + t], a1);
    }
    atomicAdd(&out[e], (a0 + a1) * (0.5f / (float)S_DIM));
}

extern "C" void kernel_launch(void* const* d_in, const int* in_sizes, int n_in,
                              void* d_out, int out_size, void* d_ws, size_t ws_size,
                              hipStream_t stream) {
    const float* text = (const float*)d_in[0];
    const float* anp  = (const float*)d_in[1];
    const float* ts   = (const float*)d_in[2];
    const float* W11  = (const float*)d_in[3];
    const float* b11  = (const float*)d_in[4];
    const float* W21  = (const float*)d_in[5];
    // d_in[6] = b21: unused, softmax is shift-invariant
    const float* W12  = (const float*)d_in[7];
    const float* b12  = (const float*)d_in[8];
    const float* W22  = (const float*)d_in[9];
    // d_in[10] = b22: unused
    float* out = (float*)d_out;

    // workspace layout (bytes): total ~53.25 MB
    char* ws = (char*)d_ws;
    unsigned short* Abf = (unsigned short*)ws;                                   // 50331648
    unsigned short* Bt  = (unsigned short*)(ws + 50331648);                      //  2162688
    float* cbias = (float*)(ws + 50331648 + 2162688);                            //   360448
    float* score = (float*)(ws + 50331648 + 2162688 + 360448);                   //   262144
    float* wsum  = (float*)(ws + 50331648 + 2162688 + 360448 + 262144);          //   131072

    hipMemsetAsync(score, 0, 2 * M_DIM * sizeof(float), stream);
    hipMemsetAsync(out, 0, B_DIM * T_DIM * sizeof(float), stream);

    convA_kernel<<<M_DIM * K_DIM / 1024, 256, 0, stream>>>(ts, Abf);
    convW_kernel<<<N_DIM * K_DIM / 256, 256, 0, stream>>>(W11, W12, Bt);
    bias_kernel<<<B_DIM * N_DIM / 256, 256, 0, stream>>>(text, anp, W11, b11, W12, b12, cbias);
    gemm_score_kernel<<<dim3(M_DIM / BM, N_DIM / BN), 256, 0, stream>>>(Abf, Bt, cbias, W21, W22, score);
    softmax_kernel<<<B_DIM, 512, 0, stream>>>(score, wsum);
    wmean_kernel<<<dim3(B_DIM * T_DIM / 256, 16), 256, 0, stream>>>(ts, wsum, out);
}

// Round 4
// 349.915 us; speedup vs baseline: 1.2528x; 1.2528x over previous
//
#include <hip/hip_runtime.h>
#include <stdint.h>

// Problem constants
#define S_DIM 512
#define B_DIM 64
#define T_DIM 768
#define A_DIM 512
#define H1_DIM 768
#define H2_DIM 640
#define N_DIM (H1_DIM + H2_DIM)   // 1408 combined hidden cols
#define M_DIM (S_DIM * B_DIM)     // 32768 rows
#define K_DIM T_DIM               // 768

typedef short s16x8 __attribute__((ext_vector_type(8)));
typedef float f32x4 __attribute__((ext_vector_type(4)));

__device__ __forceinline__ unsigned short f2bf(float f) {
    unsigned u = __float_as_uint(f);
    u += 0x7fffu + ((u >> 16) & 1u);   // round-to-nearest-even
    return (unsigned short)(u >> 16);
}

// --- convert text_seq fp32 -> bf16 (flat (M,K)) ---
__global__ __launch_bounds__(256) void convA_kernel(const float* __restrict__ ts,
                                                    unsigned short* __restrict__ Abf) {
    int i = blockIdx.x * 256 + threadIdx.x;   // over M*K/4 float4 groups
    float4 v = ((const float4*)ts)[i];
    ushort4 o;
    o.x = f2bf(v.x); o.y = f2bf(v.y); o.z = f2bf(v.z); o.w = f2bf(v.w);
    ((ushort4*)Abf)[i] = o;
}

// --- build combined B^T bf16: Bt[n][k], n<768 from W11[:T], else W12[:T] ---
__global__ __launch_bounds__(256) void convW_kernel(const float* __restrict__ W11,
                                                    const float* __restrict__ W12,
                                                    unsigned short* __restrict__ Bt) {
    int e = blockIdx.x * 256 + threadIdx.x;   // N_DIM*K_DIM
    int n = e / K_DIM, k = e % K_DIM;
    float v = (n < H1_DIM) ? W11[k * H1_DIM + n] : W12[k * H2_DIM + (n - H1_DIM)];
    Bt[e] = f2bf(v);
}

// --- per-batch bias c[b][n] = text@W11[T:] + b11 | anp@W12[T:] + b12 (fp32) ---
__global__ __launch_bounds__(256) void bias_kernel(const float* __restrict__ text,
                                                   const float* __restrict__ anp,
                                                   const float* __restrict__ W11,
                                                   const float* __restrict__ b11,
                                                   const float* __restrict__ W12,
                                                   const float* __restrict__ b12,
                                                   float* __restrict__ cbias) {
    int e = blockIdx.x * 256 + threadIdx.x;   // B_DIM*N_DIM
    int b = e / N_DIM, n = e % N_DIM;
    float a0 = 0.f, a1 = 0.f, a2 = 0.f, a3 = 0.f, base;
    if (n < H1_DIM) {
        base = b11[n];
        const float* w = W11 + (size_t)T_DIM * H1_DIM + n;
        const float* x = text + b * T_DIM;
        for (int k = 0; k < T_DIM; k += 4) {
            a0 = fmaf(x[k],     w[(size_t)k * H1_DIM],       a0);
            a1 = fmaf(x[k + 1], w[(size_t)(k + 1) * H1_DIM], a1);
            a2 = fmaf(x[k + 2], w[(size_t)(k + 2) * H1_DIM], a2);
            a3 = fmaf(x[k + 3], w[(size_t)(k + 3) * H1_DIM], a3);
        }
    } else {
        int n2 = n - H1_DIM;
        base = b12[n2];
        const float* w = W12 + (size_t)T_DIM * H2_DIM + n2;
        const float* x = anp + b * A_DIM;
        for (int k = 0; k < A_DIM; k += 4) {
            a0 = fmaf(x[k],     w[(size_t)k * H2_DIM],       a0);
            a1 = fmaf(x[k + 1], w[(size_t)(k + 1) * H2_DIM], a1);
            a2 = fmaf(x[k + 2], w[(size_t)(k + 2) * H2_DIM], a2);
            a3 = fmaf(x[k + 3], w[(size_t)(k + 3) * H2_DIM], a3);
        }
    }
    cbias[e] = base + ((a0 + a1) + (a2 + a3));
}

// --- main: bf16 MFMA GEMM with fused tanh-dot epilogue -> scores [2][B][S] ---
// LDS chunk swizzle: logical chunk c (16B) of row r is stored at chunk c^(r&7).
// Implemented on the write side via the global_load_lds SOURCE address (the LDS
// dest is hard-wired to lane*16), and on the read side via XOR on the offset.
#define BM 128
#define BN 128
#define BK 64

__global__ __launch_bounds__(256, 2) void gemm_score_kernel(
        const unsigned short* __restrict__ A,    // (M,K) bf16
        const unsigned short* __restrict__ Bt,   // (N,K) bf16
        const float* __restrict__ cbias,         // (B,N)
        const float* __restrict__ W21,           // (768)
        const float* __restrict__ W22,           // (640)
        float* __restrict__ score) {             // [2][B][S] pre-zeroed
    __shared__ __align__(16) unsigned short As[BM * BK];   // 16 KB
    __shared__ __align__(16) unsigned short Bs[BN * BK];   // 16 KB
    const int tid  = threadIdx.x;
    const int m0   = blockIdx.x * BM;
    const int n0   = blockIdx.y * BN;
    const int lane = tid & 63;
    const int wave = tid >> 6;
    const int wm   = wave & 1;       // 2x2 waves over 128x128
    const int wn   = wave >> 1;
    const int quad = lane >> 4;
    const int col  = lane & 15;
    const int cswz = col & 7;        // row&7 == col&7 for fragment rows

    f32x4 acc[4][4] = {};            // 4x4 subtiles of 16x16 per wave

    // staging: each instr covers 8 rows x 64 k (1 KB contiguous LDS)
    const int wrow = lane >> 3;                        // 0..7 row within group
    const int kof  = (((lane & 7) ^ wrow) & 7) * 8;    // swizzled source chunk

    for (int k0 = 0; k0 < K_DIM; k0 += BK) {
        #pragma unroll
        for (int p = 0; p < 4; ++p) {
            const int r0 = p * 32 + wave * 8;    // wave-uniform row group (mult of 8)
            __builtin_amdgcn_global_load_lds(
                (__attribute__((address_space(1))) void*)&A[(size_t)(m0 + r0 + wrow) * K_DIM + k0 + kof],
                (__attribute__((address_space(3))) void*)&As[r0 * BK],
                16, 0, 0);
            __builtin_amdgcn_global_load_lds(
                (__attribute__((address_space(1))) void*)&Bt[(size_t)(n0 + r0 + wrow) * K_DIM + k0 + kof],
                (__attribute__((address_space(3))) void*)&Bs[r0 * BK],
                16, 0, 0);
        }
        __syncthreads();
        #pragma unroll
        for (int kk = 0; kk < BK; kk += 32) {
            s16x8 af[4], bf[4];
            const int ch = ((kk >> 3) + quad) ^ cswz;    // stored chunk index
            #pragma unroll
            for (int i = 0; i < 4; ++i)
                af[i] = *(const s16x8*)&As[(wm * 64 + i * 16 + col) * BK + ch * 8];
            #pragma unroll
            for (int j = 0; j < 4; ++j)
                bf[j] = *(const s16x8*)&Bs[(wn * 64 + j * 16 + col) * BK + ch * 8];
            #pragma unroll
            for (int i = 0; i < 4; ++i)
                #pragma unroll
                for (int j = 0; j < 4; ++j)
                    acc[i][j] = __builtin_amdgcn_mfma_f32_16x16x32_bf16(af[i], bf[j], acc[i][j], 0, 0, 0);
        }
        __syncthreads();
    }

    // Epilogue: score[half][b][s] += sum_n tanh(acc + c[b][n]) * w2[n]
    const int half = (n0 >= H1_DIM) ? 1 : 0;     // 768 = 6*128, tiles never straddle
    const float* w2p = half ? (W22 - H1_DIM) : W21;
    int   ncol[4];
    float w2v[4];
    #pragma unroll
    for (int j = 0; j < 4; ++j) {
        ncol[j] = n0 + wn * 64 + j * 16 + col;
        w2v[j]  = w2p[ncol[j]];
    }
    float* sc = score + half * M_DIM;
    #pragma unroll
    for (int i = 0; i < 4; ++i) {
        #pragma unroll
        for (int r = 0; r < 4; ++r) {
            int row_local = wm * 64 + i * 16 + quad * 4 + r;   // C/D: row=quad*4+reg
            int b = row_local & (B_DIM - 1);                   // m0 % 128 == 0
            int s = (m0 + row_local) >> 6;
            float v = 0.f;
            #pragma unroll
            for (int j = 0; j < 4; ++j) {
                float pre = acc[i][j][r] + cbias[b * N_DIM + ncol[j]];
                float ex  = __expf(2.f * pre);                 // tanh(x)=1-2/(e^{2x}+1)
                float th  = 1.f - 2.f * __builtin_amdgcn_rcpf(ex + 1.f);
                v = fmaf(th, w2v[j], v);
            }
            v += __shfl_xor(v, 1);    // reduce over the 16 cols (same quad = same row)
            v += __shfl_xor(v, 2);
            v += __shfl_xor(v, 4);
            v += __shfl_xor(v, 8);
            if (col == 0) atomicAdd(&sc[b * S_DIM + s], v);
        }
    }
}

// --- softmax over S per (b, half); wsum[b][s] = w1 + w2; one block per b ---
__global__ __launch_bounds__(512) void softmax_kernel(const float* __restrict__ score,
                                                      float* __restrict__ wsum) {
    const int b = blockIdx.x, s = threadIdx.x;   // 512 threads = 512 s
    __shared__ float redm[16], reds[16];
    float v0 = score[b * S_DIM + s];
    float v1 = score[M_DIM + b * S_DIM + s];
    float m0 = v0, m1 = v1;
    #pragma unroll
    for (int off = 32; off > 0; off >>= 1) {
        m0 = fmaxf(m0, __shfl_xor(m0, off));
        m1 = fmaxf(m1, __shfl_xor(m1, off));
    }
    const int w = s >> 6;
    if ((s & 63) == 0) { redm[w] = m0; redm[8 + w] = m1; }
    __syncthreads();
    m0 = redm[0]; m1 = redm[8];
    #pragma unroll
    for (int i = 1; i < 8; ++i) { m0 = fmaxf(m0, redm[i]); m1 = fmaxf(m1, redm[8 + i]); }
    float e0 = expf(v0 - m0), e1 = expf(v1 - m1);
    float s0 = e0, s1 = e1;
    #pragma unroll
    for (int off = 32; off > 0; off >>= 1) {
        s0 += __shfl_xor(s0, off);
        s1 += __shfl_xor(s1, off);
    }
    if ((s & 63) == 0) { reds[w] = s0; reds[8 + w] = s1; }
    __syncthreads();
    s0 = reds[0]; s1 = reds[8];
    #pragma unroll
    for (int i = 1; i < 8; ++i) { s0 += reds[i]; s1 += reds[8 + i]; }
    wsum[b * S_DIM + s] = e0 / s0 + e1 / s1;
}

// --- out[b,t] = (0.5/S) * sum_s wsum[b][s] * Abf[s,b,t]; bf16 loads, 2 cols/thread ---
__global__ __launch_bounds__(256) void wmean_kernel(const unsigned short* __restrict__ Abf,
                                                    const float* __restrict__ wsum,
                                                    float* __restrict__ out) {
    int e = blockIdx.x * 256 + threadIdx.x;        // over B*T/2
    int s0 = blockIdx.y * 64;
    int b = e / (T_DIM / 2), tp = e % (T_DIM / 2); // tp = t/2
    const unsigned short* base = Abf + (size_t)b * T_DIM + tp * 2;
    float a0 = 0.f, a1 = 0.f, c0 = 0.f, c1 = 0.f;
    #pragma unroll 4
    for (int s = s0; s < s0 + 64; s += 2) {
        float w0 = wsum[b * S_DIM + s];
        float w1 = wsum[b * S_DIM + s + 1];
        unsigned u0 = *(const unsigned*)(base + (size_t)s * (B_DIM * T_DIM));
        unsigned u1 = *(const unsigned*)(base + (size_t)(s + 1) * (B_DIM * T_DIM));
        a0 = fmaf(w0, __uint_as_float(u0 << 16),          a0);
        a1 = fmaf(w0, __uint_as_float(u0 & 0xffff0000u),  a1);
        c0 = fmaf(w1, __uint_as_float(u1 << 16),          c0);
        c1 = fmaf(w1, __uint_as_float(u1 & 0xffff0000u),  c1);
    }
    atomicAdd(&out[b * T_DIM + tp * 2],     (a0 + c0) * (0.5f / (float)S_DIM));
    atomicAdd(&out[b * T_DIM + tp * 2 + 1], (a1 + c1) * (0.5f / (float)S_DIM));
}

extern "C" void kernel_launch(void* const* d_in, const int* in_sizes, int n_in,
                              void* d_out, int out_size, void* d_ws, size_t ws_size,
                              hipStream_t stream) {
    const float* text = (const float*)d_in[0];
    const float* anp  = (const float*)d_in[1];
    const float* ts   = (const float*)d_in[2];
    const float* W11  = (const float*)d_in[3];
    const float* b11  = (const float*)d_in[4];
    const float* W21  = (const float*)d_in[5];
    // d_in[6] = b21: unused, softmax is shift-invariant
    const float* W12  = (const float*)d_in[7];
    const float* b12  = (const float*)d_in[8];
    const float* W22  = (const float*)d_in[9];
    // d_in[10] = b22: unused
    float* out = (float*)d_out;

    // workspace layout (bytes): total ~53.25 MB
    char* ws = (char*)d_ws;
    unsigned short* Abf = (unsigned short*)ws;                                   // 50331648
    unsigned short* Bt  = (unsigned short*)(ws + 50331648);                      //  2162688
    float* cbias = (float*)(ws + 50331648 + 2162688);                            //   360448
    float* score = (float*)(ws + 50331648 + 2162688 + 360448);                   //   262144
    float* wsum  = (float*)(ws + 50331648 + 2162688 + 360448 + 262144);          //   131072

    hipMemsetAsync(score, 0, 2 * M_DIM * sizeof(float), stream);
    hipMemsetAsync(out, 0, B_DIM * T_DIM * sizeof(float), stream);

    convA_kernel<<<M_DIM * K_DIM / 1024, 256, 0, stream>>>(ts, Abf);
    convW_kernel<<<N_DIM * K_DIM / 256, 256, 0, stream>>>(W11, W12, Bt);
    bias_kernel<<<B_DIM * N_DIM / 256, 256, 0, stream>>>(text, anp, W11, b11, W12, b12, cbias);
    gemm_score_kernel<<<dim3(M_DIM / BM, N_DIM / BN), 256, 0, stream>>>(Abf, Bt, cbias, W21, W22, score);
    softmax_kernel<<<B_DIM, 512, 0, stream>>>(score, wsum);
    wmean_kernel<<<dim3(B_DIM * T_DIM / 512, 8), 256, 0, stream>>>(Abf, wsum, out);
}